// Round 1
// baseline (818.367 us; speedup 1.0000x reference)
//
#include <hip/hip_runtime.h>

namespace {
constexpr int BF = 4;        // frames
constexpr int NA = 4000;     // atoms per frame
constexpr int NKk = 28;      // k cutoff index
constexpr int AD = 29;       // kx: 0..28
constexpr int CD = 57;       // ky/kz: -28..28
constexpr int CELLS = CD * CD;          // 3249
constexpr int NCHUNK = 8;               // atom chunks per frame
constexpr int CHUNK = NA / NCHUNK;      // 500
constexpr float TWOPI_F = 6.28318530717958647692f;
constexpr float FPI = 39.47841760435743f;        // (2*pi)^2, f64 rounded to f32
constexpr float KSQMAX = 9.869604401089358f;     // (2*pi/2)^2
constexpr float SELF_C = 0.06349363593424097f;   // 1 / (sigma * (2*pi)^1.5)
}

// ---------------------------------------------------------------------------
// Kernel 1: partial structure factors.
// Grid: (frame f, kx index a, atom chunk) = BF*AD*NCHUNK blocks, 256 threads.
// Each thread owns b = lane (0..56) and 15 c-cells (quad = tid/64).
// ---------------------------------------------------------------------------
__global__ __launch_bounds__(256)
void ew_partialS(const float* __restrict__ pos, const float* __restrict__ q,
                 const float* __restrict__ cm, float2* __restrict__ ps)
{
  const int bid = blockIdx.x;
  const int chunk = bid % NCHUNK;
  const int a = (bid / NCHUNK) % AD;
  const int f = bid / (NCHUNK * AD);
  const int tid = threadIdx.x;
  const int lane = tid & 63;
  const int quad = tid >> 6;      // 0..3, uniform per wave
  const int c0 = quad * 15;

  const float bx = cm[f * 9 + 0], by = cm[f * 9 + 4], bz = cm[f * 9 + 8];

  __shared__ float sYr[64][CD], sYi[64][CD];
  __shared__ float sZr[64][CD], sZi[64][CD];
  __shared__ float sTr[64], sTi[64];

  float accr[15], acci[15];
#pragma unroll
  for (int j = 0; j < 15; ++j) { accr[j] = 0.f; acci[j] = 0.f; }

  const int atom0 = chunk * CHUNK;
  for (int t0 = 0; t0 < CHUNK; t0 += 64) {
    const int ntile = min(64, CHUNK - t0);
    __syncthreads();   // protect LDS from previous tile's readers
    if (tid < 64) {
      // eiky table for atom (tid) via complex recurrence
      const int ai = tid;
      const bool ok = ai < ntile;
      const int gn = f * NA + atom0 + t0 + ai;
      const float y = ok ? pos[gn * 3 + 1] : 0.f;
      float rev = y / by; rev -= floorf(rev);
      float s, c; __sincosf(TWOPI_F * rev, &s, &c);
      sYr[ai][NKk] = 1.f; sYi[ai][NKk] = 0.f;
      float pr = 1.f, pi = 0.f;
      for (int j = 1; j <= NKk; ++j) {
        const float nr = pr * c - pi * s;
        const float ni = pr * s + pi * c;
        pr = nr; pi = ni;
        sYr[ai][NKk + j] = pr; sYi[ai][NKk + j] = pi;
        sYr[ai][NKk - j] = pr; sYi[ai][NKk - j] = -pi;
      }
    } else if (tid < 128) {
      // eikz table
      const int ai = tid - 64;
      const bool ok = ai < ntile;
      const int gn = f * NA + atom0 + t0 + ai;
      const float z = ok ? pos[gn * 3 + 2] : 0.f;
      float rev = z / bz; rev -= floorf(rev);
      float s, c; __sincosf(TWOPI_F * rev, &s, &c);
      sZr[ai][NKk] = 1.f; sZi[ai][NKk] = 0.f;
      float pr = 1.f, pi = 0.f;
      for (int j = 1; j <= NKk; ++j) {
        const float nr = pr * c - pi * s;
        const float ni = pr * s + pi * c;
        pr = nr; pi = ni;
        sZr[ai][NKk + j] = pr; sZi[ai][NKk + j] = pi;
        sZr[ai][NKk - j] = pr; sZi[ai][NKk - j] = -pi;
      }
    } else if (tid < 192) {
      // t = q * exp(2*pi*i * a * rx)
      const int ai = tid - 128;
      const bool ok = ai < ntile;
      const int gn = f * NA + atom0 + t0 + ai;
      const float x = ok ? pos[gn * 3 + 0] : 0.f;
      const float qq = ok ? q[gn] : 0.f;
      float rev = (float)a * (x / bx); rev -= floorf(rev);
      float s, c; __sincosf(TWOPI_F * rev, &s, &c);
      sTr[ai] = qq * c; sTi[ai] = qq * s;
    }
    __syncthreads();
    if (lane < CD) {
      for (int n = 0; n < ntile; ++n) {
        const float tr = sTr[n], tii = sTi[n];          // broadcast
        const float yr = sYr[n][lane], yi = sYi[n][lane]; // 2-way alias, free
        const float ur = tr * yr - tii * yi;
        const float ui = tr * yi + tii * yr;
#pragma unroll
        for (int j = 0; j < 15; ++j) {
          const int cc = c0 + j;
          if (cc < CD) {
            const float zr = sZr[n][cc], zi = sZi[n][cc]; // broadcast
            accr[j] = fmaf(ur, zr, accr[j]);
            accr[j] = fmaf(-ui, zi, accr[j]);
            acci[j] = fmaf(ur, zi, acci[j]);
            acci[j] = fmaf(ui, zr, acci[j]);
          }
        }
      }
    }
  }
  if (lane < CD) {
    const size_t base = (((size_t)f * AD + a) * NCHUNK + chunk) * (size_t)CELLS;
#pragma unroll
    for (int j = 0; j < 15; ++j) {
      const int cc = c0 + j;
      if (cc < CD) ps[base + (size_t)lane * CD + cc] = make_float2(accr[j], acci[j]);
    }
  }
}

// ---------------------------------------------------------------------------
// Kernel 2: reduce chunk partials, apply k-space weights, sum per frame.
// ---------------------------------------------------------------------------
__global__ __launch_bounds__(256)
void ew_reduce(const float2* __restrict__ ps, const float* __restrict__ cm,
               float* __restrict__ out)
{
  const int f = blockIdx.y;
  const int i = blockIdx.x * 256 + threadIdx.x;
  float val = 0.f;
  if (i < AD * CELLS) {
    const int a = i / CELLS;
    const int cell = i - a * CELLS;
    const int bv = cell / CD - NKk;
    const int cv = cell % CD - NKk;
    float Sr = 0.f, Si = 0.f;
    const size_t base = (((size_t)f * AD + a) * NCHUNK) * (size_t)CELLS + cell;
    for (int ch = 0; ch < NCHUNK; ++ch) {
      const float2 p = ps[base + (size_t)ch * CELLS];
      Sr += p.x; Si += p.y;
    }
    const float bx = cm[f * 9 + 0], by = cm[f * 9 + 4], bz = cm[f * 9 + 8];
    const float ksq = FPI * ((float)(a * a) / (bx * bx)
                           + (float)(bv * bv) / (by * by)
                           + (float)(cv * cv) / (bz * bz));
    if (ksq > 0.f && ksq <= KSQMAX) {
      const float w = __expf(-0.5f * ksq) / ksq * ((a > 0) ? 2.f : 1.f)
                      / (bx * by * bz);
      val = w * (Sr * Sr + Si * Si);
    }
  }
  // block reduce
  for (int off = 32; off > 0; off >>= 1) val += __shfl_down(val, off);
  __shared__ float wsum[4];
  const int w = threadIdx.x >> 6;
  if ((threadIdx.x & 63) == 0) wsum[w] = val;
  __syncthreads();
  if (threadIdx.x == 0) {
    atomicAdd(&out[f], wsum[0] + wsum[1] + wsum[2] + wsum[3]);
  }
}

// ---------------------------------------------------------------------------
// Kernel 3: Gaussian self-interaction.
// ---------------------------------------------------------------------------
__global__ __launch_bounds__(256)
void ew_self(const float* __restrict__ q, float* __restrict__ out)
{
  const int f = blockIdx.x;
  float s = 0.f;
  for (int i = threadIdx.x; i < NA; i += 256) {
    const float qq = q[f * NA + i];
    s += qq * qq;
  }
  for (int off = 32; off > 0; off >>= 1) s += __shfl_down(s, off);
  __shared__ float wsum[4];
  const int w = threadIdx.x >> 6;
  if ((threadIdx.x & 63) == 0) wsum[w] = s;
  __syncthreads();
  if (threadIdx.x == 0) {
    atomicAdd(&out[f], -(wsum[0] + wsum[1] + wsum[2] + wsum[3]) * SELF_C);
  }
}

extern "C" void kernel_launch(void* const* d_in, const int* in_sizes, int n_in,
                              void* d_out, int out_size, void* d_ws, size_t ws_size,
                              hipStream_t stream) {
  const float* pos = (const float*)d_in[0];   // (B*N, 3)
  const float* q   = (const float*)d_in[1];   // (B*N, 1)
  const float* cm  = (const float*)d_in[2];   // (B, 3, 3)
  // d_in[3] = batch: block-sorted, equal counts -> layout is static, unused
  float* out = (float*)d_out;                 // (B,)
  float2* ps = (float2*)d_ws;                 // (B, AD, NCHUNK, CELLS) complex

  hipMemsetAsync(d_out, 0, out_size * sizeof(float), stream);
  ew_partialS<<<dim3(BF * AD * NCHUNK), 256, 0, stream>>>(pos, q, cm, ps);
  ew_reduce<<<dim3((AD * CELLS + 255) / 256, BF), 256, 0, stream>>>(ps, cm, out);
  ew_self<<<dim3(BF), 256, 0, stream>>>(q, out);
}

// Round 2
// 252.556 us; speedup vs baseline: 3.2403x; 3.2403x over previous
//
#include <hip/hip_runtime.h>

namespace {
constexpr int BF = 4;        // frames
constexpr int NA = 4000;     // atoms per frame
constexpr int NKk = 28;      // k cutoff index
constexpr int AD = 29;       // kx: 0..28
constexpr int CD = 57;       // ky/kz: -28..28
constexpr int CELLS = CD * CD;          // 3249
constexpr int TILE = 50;                // atoms staged per LDS tile
constexpr int NP = 51;                  // padded tile stride (odd -> conflict-free)
constexpr float TWOPI_F = 6.28318530717958647692f;
constexpr float FPI = 39.47841760435743f;        // (2*pi)^2
constexpr float KSQMAX = 9.869604401089358f;     // (2*pi/2)^2
constexpr float SELF_C = 0.06349363593424097f;   // 1 / (sigma * (2*pi)^1.5)
}

// ---------------------------------------------------------------------------
// Kernel 1: partial structure factors, register-tiled.
// Grid: BF * 8 * nchunk blocks, 256 threads. Wave w handles a = ag + 8*w.
// Thread (tb,tc) = (lane/8, lane%8) owns b = tb+8i, c = tc+8j (8x8 complex acc).
// Per atom: 17 ds_read_b64 for 256 FMAs (vs 34 b32 per 60 in R1).
// ---------------------------------------------------------------------------
__global__ __launch_bounds__(256, 2)
void ew_partialS(const float* __restrict__ pos, const float* __restrict__ q,
                 const float* __restrict__ cm, float2* __restrict__ ps,
                 int nchunk, int chunk_sz)
{
  const int bid = blockIdx.x;
  const int chunk = bid % nchunk;
  const int ag = (bid / nchunk) & 7;
  const int f = bid / (nchunk * 8);
  const int tid = threadIdx.x;
  const int w = tid >> 6;
  const int lane = tid & 63;
  const int a = ag + 8 * w;            // 0..31; a>=29 -> wave idle in compute
  const int tb = lane >> 3;            // 0..7
  const int tc = lane & 7;             // 0..7

  const float bx = cm[f * 9 + 0], by = cm[f * 9 + 4], bz = cm[f * 9 + 8];

  __shared__ float2 sY[64 * NP];       // [b][n], row stride 408B -> bank stride 6
  __shared__ float2 sZ[64 * NP];
  __shared__ float2 sPQ[TILE];         // (x/bx, q)

  float accr[8][8], acci[8][8];
#pragma unroll
  for (int i = 0; i < 8; ++i)
#pragma unroll
    for (int j = 0; j < 8; ++j) { accr[i][j] = 0.f; acci[i][j] = 0.f; }

  const int atom0 = chunk * chunk_sz;
  for (int t0 = 0; t0 < chunk_sz; t0 += TILE) {
    __syncthreads();
    if (tid < TILE) {
      // eiky table for atom tid, transposed layout
      const int gn = f * NA + atom0 + t0 + tid;
      const float y = pos[gn * 3 + 1];
      float rev = y / by; rev -= floorf(rev);
      float s, c; __sincosf(TWOPI_F * rev, &s, &c);
      sY[NKk * NP + tid] = make_float2(1.f, 0.f);
      float pr = 1.f, pi = 0.f;
      for (int j = 1; j <= NKk; ++j) {
        const float nr = pr * c - pi * s;
        const float ni = pr * s + pi * c;
        pr = nr; pi = ni;
        sY[(NKk + j) * NP + tid] = make_float2(pr, pi);
        sY[(NKk - j) * NP + tid] = make_float2(pr, -pi);
      }
      for (int b = CD; b < 64; ++b) sY[b * NP + tid] = make_float2(0.f, 0.f);
    } else if (tid >= 64 && tid < 64 + TILE) {
      const int ai = tid - 64;
      const int gn = f * NA + atom0 + t0 + ai;
      const float z = pos[gn * 3 + 2];
      float rev = z / bz; rev -= floorf(rev);
      float s, c; __sincosf(TWOPI_F * rev, &s, &c);
      sZ[NKk * NP + ai] = make_float2(1.f, 0.f);
      float pr = 1.f, pi = 0.f;
      for (int j = 1; j <= NKk; ++j) {
        const float nr = pr * c - pi * s;
        const float ni = pr * s + pi * c;
        pr = nr; pi = ni;
        sZ[(NKk + j) * NP + ai] = make_float2(pr, pi);
        sZ[(NKk - j) * NP + ai] = make_float2(pr, -pi);
      }
      for (int b = CD; b < 64; ++b) sZ[b * NP + ai] = make_float2(0.f, 0.f);
    } else if (tid >= 128 && tid < 128 + TILE) {
      const int ai = tid - 128;
      const int gn = f * NA + atom0 + t0 + ai;
      sPQ[ai] = make_float2(pos[gn * 3 + 0] / bx, q[gn]);
    }
    __syncthreads();
    if (a < AD) {
      const float af = (float)a;
      for (int n = 0; n < TILE; ++n) {
        const float2 pq = sPQ[n];                        // broadcast
        float rev = af * pq.x; rev -= floorf(rev);
        float s, c; __sincosf(TWOPI_F * rev, &s, &c);
        const float tr = pq.y * c, ti = pq.y * s;
        float2 yv[8], zv[8];
#pragma unroll
        for (int i = 0; i < 8; ++i) yv[i] = sY[(tb + 8 * i) * NP + n];
#pragma unroll
        for (int j = 0; j < 8; ++j) zv[j] = sZ[(tc + 8 * j) * NP + n];
        float ur[8], ui[8];
#pragma unroll
        for (int i = 0; i < 8; ++i) {
          ur[i] = tr * yv[i].x - ti * yv[i].y;
          ui[i] = tr * yv[i].y + ti * yv[i].x;
        }
#pragma unroll
        for (int i = 0; i < 8; ++i)
#pragma unroll
          for (int j = 0; j < 8; ++j) {
            accr[i][j] = fmaf(ur[i], zv[j].x, fmaf(-ui[i], zv[j].y, accr[i][j]));
            acci[i][j] = fmaf(ur[i], zv[j].y, fmaf(ui[i], zv[j].x, acci[i][j]));
          }
      }
    }
  }
  if (a < AD) {
    const size_t base = (((size_t)f * AD + a) * nchunk + chunk) * (size_t)CELLS;
#pragma unroll
    for (int i = 0; i < 8; ++i) {
      const int b = tb + 8 * i;
      if (b < CD) {
#pragma unroll
        for (int j = 0; j < 8; ++j) {
          const int c = tc + 8 * j;
          if (c < CD) ps[base + b * CD + c] = make_float2(accr[i][j], acci[i][j]);
        }
      }
    }
  }
}

// ---------------------------------------------------------------------------
// Kernel 2: reduce chunk partials, apply k-space weights, sum per frame.
// ---------------------------------------------------------------------------
__global__ __launch_bounds__(256)
void ew_reduce(const float2* __restrict__ ps, const float* __restrict__ cm,
               float* __restrict__ out, int nchunk)
{
  const int f = blockIdx.y;
  const int i = blockIdx.x * 256 + threadIdx.x;
  float val = 0.f;
  if (i < AD * CELLS) {
    const int a = i / CELLS;
    const int cell = i - a * CELLS;
    const int bv = cell / CD - NKk;
    const int cv = cell % CD - NKk;
    float Sr = 0.f, Si = 0.f;
    const size_t base = (((size_t)f * AD + a) * nchunk) * (size_t)CELLS + cell;
    for (int ch = 0; ch < nchunk; ++ch) {
      const float2 p = ps[base + (size_t)ch * CELLS];
      Sr += p.x; Si += p.y;
    }
    const float bx = cm[f * 9 + 0], by = cm[f * 9 + 4], bz = cm[f * 9 + 8];
    const float ksq = FPI * ((float)(a * a) / (bx * bx)
                           + (float)(bv * bv) / (by * by)
                           + (float)(cv * cv) / (bz * bz));
    if (ksq > 0.f && ksq <= KSQMAX) {
      const float w = __expf(-0.5f * ksq) / ksq * ((a > 0) ? 2.f : 1.f)
                      / (bx * by * bz);
      val = w * (Sr * Sr + Si * Si);
    }
  }
  for (int off = 32; off > 0; off >>= 1) val += __shfl_down(val, off);
  __shared__ float wsum[4];
  const int wv = threadIdx.x >> 6;
  if ((threadIdx.x & 63) == 0) wsum[wv] = val;
  __syncthreads();
  if (threadIdx.x == 0) {
    atomicAdd(&out[f], wsum[0] + wsum[1] + wsum[2] + wsum[3]);
  }
}

// ---------------------------------------------------------------------------
// Kernel 3: Gaussian self-interaction.
// ---------------------------------------------------------------------------
__global__ __launch_bounds__(256)
void ew_self(const float* __restrict__ q, float* __restrict__ out)
{
  const int f = blockIdx.x;
  float s = 0.f;
  for (int i = threadIdx.x; i < NA; i += 256) {
    const float qq = q[f * NA + i];
    s += qq * qq;
  }
  for (int off = 32; off > 0; off >>= 1) s += __shfl_down(s, off);
  __shared__ float wsum[4];
  const int wv = threadIdx.x >> 6;
  if ((threadIdx.x & 63) == 0) wsum[wv] = s;
  __syncthreads();
  if (threadIdx.x == 0) {
    atomicAdd(&out[f], -(wsum[0] + wsum[1] + wsum[2] + wsum[3]) * SELF_C);
  }
}

extern "C" void kernel_launch(void* const* d_in, const int* in_sizes, int n_in,
                              void* d_out, int out_size, void* d_ws, size_t ws_size,
                              hipStream_t stream) {
  const float* pos = (const float*)d_in[0];   // (B*N, 3)
  const float* q   = (const float*)d_in[1];   // (B*N, 1)
  const float* cm  = (const float*)d_in[2];   // (B, 3, 3)
  float* out = (float*)d_out;                 // (B,)
  float2* ps = (float2*)d_ws;                 // (B, AD, nchunk, CELLS) complex

  const size_t need16 = (size_t)BF * AD * 16 * CELLS * sizeof(float2); // 48.2 MB
  const int nchunk = (ws_size >= need16) ? 16 : 8;
  const int chunk_sz = NA / nchunk;

  hipMemsetAsync(d_out, 0, out_size * sizeof(float), stream);
  ew_partialS<<<dim3(BF * 8 * nchunk), 256, 0, stream>>>(pos, q, cm, ps, nchunk, chunk_sz);
  ew_reduce<<<dim3((AD * CELLS + 255) / 256, BF), 256, 0, stream>>>(ps, cm, out, nchunk);
  ew_self<<<dim3(BF), 256, 0, stream>>>(q, out);
}

// Round 3
// 232.145 us; speedup vs baseline: 3.5252x; 1.0879x over previous
//
#include <hip/hip_runtime.h>

namespace {
constexpr int BF = 4;        // frames
constexpr int NA = 4000;     // atoms per frame
constexpr int NPAD = 4096;   // padded K
constexpr int N8 = NPAD / 8; // 512 k-groups
constexpr int AD = 29;       // kx: 0..28
constexpr int CD = 57;       // ky/kz: -28..28 (index - 28)
constexpr float TWOPI_F = 6.28318530717958647692f;
constexpr float FPI = 39.47841760435743f;        // (2*pi)^2
constexpr float KSQMAX = 9.869604401089358f;     // (2*pi/2)^2
constexpr float SELF_C = 0.06349363593424097f;   // 1 / (sigma * (2*pi)^1.5)

// table element counts
constexpr size_t YSTR = (size_t)N8 * 64 * 8;     // per-frame elements = 262144
}

typedef short bfrag __attribute__((ext_vector_type(8)));   // 8 bf16 (4 VGPR)
typedef float f32x4 __attribute__((ext_vector_type(4)));

__device__ __forceinline__ unsigned short f2bf(float x) {  // RNE f32->bf16
  unsigned u = __float_as_uint(x);
  u += 0x7fffu + ((u >> 16) & 1u);
  return (unsigned short)(u >> 16);
}
__device__ __forceinline__ float2 cmul(float2 a, float2 b) {
  return make_float2(a.x * b.x - a.y * b.y, a.x * b.y + a.y * b.x);
}

// ---------------------------------------------------------------------------
// Prep: per atom build Y (f32, frag layout), Z (bf16, frag layout), T tables.
// Layout [f][n8][col][i] with n = n8*8+i; col = b or c index (0..56 used).
// ---------------------------------------------------------------------------
__global__ __launch_bounds__(256)
void ew_prep(const float* __restrict__ pos, const float* __restrict__ q,
             const float* __restrict__ cm,
             float* __restrict__ Yfr, float* __restrict__ Yfi,
             unsigned short* __restrict__ Zpr, unsigned short* __restrict__ Zpi,
             float2* __restrict__ T)
{
  const int f = blockIdx.y;
  const int n = blockIdx.x * 256 + threadIdx.x;   // 0..4095
  const float bx = cm[f * 9 + 0], by = cm[f * 9 + 4], bz = cm[f * 9 + 8];
  float x = 0.f, y = 0.f, z = 0.f, qq = 0.f;
  if (n < NA) {
    const int gn = f * NA + n;
    x = pos[gn * 3 + 0]; y = pos[gn * 3 + 1]; z = pos[gn * 3 + 2];
    qq = q[gn];
  }
  const float vmask = (n < NA) ? 1.f : 0.f;
  const size_t base = (size_t)f * YSTR + (size_t)(n >> 3) * 512 + (n & 7);

  {  // Y table: e^{i(col-28)*theta_y}, f32
    float rev = y / by; rev -= floorf(rev);
    float s, c; __sincosf(TWOPI_F * rev, &s, &c);
    const float2 p = make_float2(c, s);
    const float2 p2 = cmul(p, p), p4 = cmul(p2, p2), p8 = cmul(p4, p4);
    const float2 p16 = cmul(p8, p8), p24 = cmul(p16, p8), p28 = cmul(p24, p4);
    float2 cur = make_float2(p28.x * vmask, -p28.y * vmask);  // conj, masked
    for (int col = 0; col < CD; ++col) {
      Yfr[base + (size_t)col * 8] = cur.x;
      Yfi[base + (size_t)col * 8] = cur.y;
      cur = cmul(cur, p);
    }
    for (int col = CD; col < 64; ++col) {
      Yfr[base + (size_t)col * 8] = 0.f;
      Yfi[base + (size_t)col * 8] = 0.f;
    }
  }
  {  // Z table: e^{i(col-28)*theta_z}, bf16
    float rev = z / bz; rev -= floorf(rev);
    float s, c; __sincosf(TWOPI_F * rev, &s, &c);
    const float2 p = make_float2(c, s);
    const float2 p2 = cmul(p, p), p4 = cmul(p2, p2), p8 = cmul(p4, p4);
    const float2 p16 = cmul(p8, p8), p24 = cmul(p16, p8), p28 = cmul(p24, p4);
    float2 cur = make_float2(p28.x * vmask, -p28.y * vmask);
    for (int col = 0; col < CD; ++col) {
      Zpr[base + (size_t)col * 8] = f2bf(cur.x);
      Zpi[base + (size_t)col * 8] = f2bf(cur.y);
      cur = cmul(cur, p);
    }
    for (int col = CD; col < 64; ++col) {
      Zpr[base + (size_t)col * 8] = 0;
      Zpi[base + (size_t)col * 8] = 0;
    }
  }
  {  // T table: q * e^{i*a*theta_x}, fp32, [f][a][n]
    float rev = x / bx; rev -= floorf(rev);
    float s, c; __sincosf(TWOPI_F * rev, &s, &c);
    const float2 p = make_float2(c, s);
    float2 cur = make_float2(qq, 0.f);
    for (int a = 0; a < AD; ++a) {
      T[((size_t)f * AD + a) * NPAD + n] = cur;
      cur = cmul(cur, p);
    }
  }
}

// ---------------------------------------------------------------------------
// MFMA S-accumulation + weighted reduce. One block per (a, f), 4 waves.
// Wave w: b-strip [16w, 16w+16). Sr/Si: 4 c-tiles of f32x4 each.
// ---------------------------------------------------------------------------
__global__ __launch_bounds__(256)
void ew_smfma(const float* __restrict__ Yfr, const float* __restrict__ Yfi,
              const unsigned short* __restrict__ Zpr,
              const unsigned short* __restrict__ Zpi,
              const float2* __restrict__ T, const float* __restrict__ cm,
              float* __restrict__ out)
{
  const int a = blockIdx.x, f = blockIdx.y;
  const int tid = threadIdx.x;
  const int w = tid >> 6, lane = tid & 63;
  const int g = lane >> 4, r16 = lane & 15;
  const int b0 = 16 * w;

  f32x4 Sr[4], Si[4];
#pragma unroll
  for (int ct = 0; ct < 4; ++ct) {
    Sr[ct] = (f32x4){0.f, 0.f, 0.f, 0.f};
    Si[ct] = (f32x4){0.f, 0.f, 0.f, 0.f};
  }

  const size_t ybase = (size_t)f * YSTR + (size_t)(b0 + r16) * 8 + (size_t)g * 512;
  const size_t zbase = (size_t)f * YSTR + (size_t)r16 * 8 + (size_t)g * 512;
  const float2* tp = T + ((size_t)f * AD + a) * NPAD + g * 8;

  for (int kt = 0; kt < NPAD / 32; ++kt) {
    const size_t ko = (size_t)kt * 2048;          // 4 n8-groups * 512 elems
    // T: 8 consecutive float2 (64B)
    const float4* t4 = (const float4*)(tp + (size_t)kt * 32);
    const float4 t01 = t4[0], t23 = t4[1], t45 = t4[2], t67 = t4[3];
    // Y: 8 f32 each component
    const float4* yr4 = (const float4*)(Yfr + ybase + ko);
    const float4* yi4 = (const float4*)(Yfi + ybase + ko);
    const float4 yra = yr4[0], yrb = yr4[1];
    const float4 yia = yi4[0], yib = yi4[1];

    const float tr[8] = {t01.x, t01.z, t23.x, t23.z, t45.x, t45.z, t67.x, t67.z};
    const float ti[8] = {t01.y, t01.w, t23.y, t23.w, t45.y, t45.w, t67.y, t67.w};
    const float yr[8] = {yra.x, yra.y, yra.z, yra.w, yrb.x, yrb.y, yrb.z, yrb.w};
    const float yi[8] = {yia.x, yia.y, yia.z, yia.w, yib.x, yib.y, yib.z, yib.w};

    float ur[8], ui[8];
#pragma unroll
    for (int i = 0; i < 8; ++i) {
      const float m = ti[i] * yi[i];
      ur[i] = fmaf(tr[i], yr[i], -m);
      ui[i] = fmaf(tr[i], yi[i], ti[i] * yr[i]);
    }
    union { unsigned u[4]; bfrag v; } UR, UI, UN;
#pragma unroll
    for (int k = 0; k < 4; ++k) {
      asm("v_cvt_pk_bf16_f32 %0, %1, %2" : "=v"(UR.u[k]) : "v"(ur[2*k]), "v"(ur[2*k+1]));
      asm("v_cvt_pk_bf16_f32 %0, %1, %2" : "=v"(UI.u[k]) : "v"(ui[2*k]), "v"(ui[2*k+1]));
    }
#pragma unroll
    for (int k = 0; k < 4; ++k) UN.u[k] = UI.u[k] ^ 0x80008000u;

#pragma unroll
    for (int ct = 0; ct < 4; ++ct) {
      const bfrag Zr8 = *(const bfrag*)(Zpr + zbase + ko + (size_t)ct * 128);
      const bfrag Zi8 = *(const bfrag*)(Zpi + zbase + ko + (size_t)ct * 128);
      Sr[ct] = __builtin_amdgcn_mfma_f32_16x16x32_bf16(UR.v, Zr8, Sr[ct], 0, 0, 0);
      Sr[ct] = __builtin_amdgcn_mfma_f32_16x16x32_bf16(UN.v, Zi8, Sr[ct], 0, 0, 0);
      Si[ct] = __builtin_amdgcn_mfma_f32_16x16x32_bf16(UR.v, Zi8, Si[ct], 0, 0, 0);
      Si[ct] = __builtin_amdgcn_mfma_f32_16x16x32_bf16(UI.v, Zr8, Si[ct], 0, 0, 0);
    }
  }

  // ---- weighted reduce (same formula/order as validated R2 reduce) ----
  const float bx = cm[f * 9 + 0], by = cm[f * 9 + 4], bz = cm[f * 9 + 8];
  const float invV = 1.f / (bx * by * bz);
  const float fac = (a > 0) ? 2.f : 1.f;
  const float aterm = (float)(a * a) / (bx * bx);
  float val = 0.f;
#pragma unroll
  for (int ct = 0; ct < 4; ++ct) {
    const int cv = ct * 16 + r16 - 28;
    const float cterm = (float)(cv * cv) / (bz * bz);
#pragma unroll
    for (int rg = 0; rg < 4; ++rg) {
      const int bv = b0 + 4 * g + rg - 28;
      const float ksq = FPI * (aterm + (float)(bv * bv) / (by * by) + cterm);
      if (ksq > 0.f && ksq <= KSQMAX) {
        const float wgt = __expf(-0.5f * ksq) / ksq * fac * invV;
        val = fmaf(wgt, Sr[ct][rg] * Sr[ct][rg] + Si[ct][rg] * Si[ct][rg], val);
      }
    }
  }
  for (int off = 32; off > 0; off >>= 1) val += __shfl_down(val, off);
  __shared__ float wsum[4];
  if (lane == 0) wsum[w] = val;
  __syncthreads();
  if (tid == 0) atomicAdd(&out[f], wsum[0] + wsum[1] + wsum[2] + wsum[3]);
}

// ---------------------------------------------------------------------------
// Self-interaction.
// ---------------------------------------------------------------------------
__global__ __launch_bounds__(256)
void ew_self(const float* __restrict__ q, float* __restrict__ out)
{
  const int f = blockIdx.x;
  float s = 0.f;
  for (int i = threadIdx.x; i < NA; i += 256) {
    const float qq = q[f * NA + i];
    s += qq * qq;
  }
  for (int off = 32; off > 0; off >>= 1) s += __shfl_down(s, off);
  __shared__ float wsum[4];
  const int wv = threadIdx.x >> 6;
  if ((threadIdx.x & 63) == 0) wsum[wv] = s;
  __syncthreads();
  if (threadIdx.x == 0)
    atomicAdd(&out[f], -(wsum[0] + wsum[1] + wsum[2] + wsum[3]) * SELF_C);
}

extern "C" void kernel_launch(void* const* d_in, const int* in_sizes, int n_in,
                              void* d_out, int out_size, void* d_ws, size_t ws_size,
                              hipStream_t stream) {
  const float* pos = (const float*)d_in[0];   // (B*N, 3)
  const float* q   = (const float*)d_in[1];   // (B*N, 1)
  const float* cm  = (const float*)d_in[2];   // (B, 3, 3)
  float* out = (float*)d_out;                 // (B,)

  char* ws = (char*)d_ws;
  float* Yfr = (float*)(ws);                                   // 4 MB
  float* Yfi = (float*)(ws + (size_t)4 * 1024 * 1024);         // 4 MB
  unsigned short* Zpr = (unsigned short*)(ws + (size_t)8 * 1024 * 1024);   // 2 MB
  unsigned short* Zpi = (unsigned short*)(ws + (size_t)10 * 1024 * 1024);  // 2 MB
  float2* T = (float2*)(ws + (size_t)12 * 1024 * 1024);        // 3.8 MB

  hipMemsetAsync(d_out, 0, out_size * sizeof(float), stream);
  ew_prep<<<dim3(NPAD / 256, BF), 256, 0, stream>>>(pos, q, cm, Yfr, Yfi, Zpr, Zpi, T);
  ew_smfma<<<dim3(AD, BF), 256, 0, stream>>>(Yfr, Yfi, Zpr, Zpi, T, cm, out);
  ew_self<<<dim3(BF), 256, 0, stream>>>(q, out);
}

// Round 4
// 88.662 us; speedup vs baseline: 9.2302x; 2.6183x over previous
//
#include <hip/hip_runtime.h>

namespace {
constexpr int BF = 4;        // frames
constexpr int NA = 4000;     // atoms per frame
constexpr int NPAD = 4096;   // padded K
constexpr int N8 = NPAD / 8; // 512 k-groups
constexpr int AD = 29;       // kx: 0..28
constexpr int CD = 57;       // ky/kz: -28..28 (index - 28)
constexpr int NCH = 8;       // K-chunks
constexpr int KT_PER_CH = (NPAD / 32) / NCH;  // 16 k-tiles per chunk
constexpr float TWOPI_F = 6.28318530717958647692f;
constexpr float FPI = 39.47841760435743f;        // (2*pi)^2
constexpr float KSQMAX = 9.869604401089358f;     // (2*pi/2)^2
constexpr float SELF_C = 0.06349363593424097f;   // 1 / (sigma * (2*pi)^1.5)
constexpr size_t YSTR = (size_t)N8 * 64 * 8;     // per-frame table elems = 262144
constexpr size_t SPLANE = (size_t)BF * AD * 4096; // S elems per chunk
}

typedef short bfrag __attribute__((ext_vector_type(8)));   // 8 bf16 (4 VGPR)
typedef float f32x4 __attribute__((ext_vector_type(4)));
typedef unsigned short u16x8 __attribute__((ext_vector_type(8)));

__device__ __forceinline__ unsigned short f2bf(float x) {  // RNE f32->bf16
  unsigned u = __float_as_uint(x);
  u += 0x7fffu + ((u >> 16) & 1u);
  return (unsigned short)(u >> 16);
}
__device__ __forceinline__ float2 cmul(float2 a, float2 b) {
  return make_float2(a.x * b.x - a.y * b.y, a.x * b.y + a.y * b.x);
}
// p^m for m in [0,31] via square-and-select (branch-free-ish)
__device__ __forceinline__ float2 cpow_m(float c, float s, int m) {
  float2 r = make_float2(1.f, 0.f);
  float2 x = make_float2(c, s);
  if (m & 1) r = x;
#pragma unroll
  for (int b = 1; b < 5; ++b) {
    x = cmul(x, x);
    const float2 t = cmul(r, x);
    if (m & (1 << b)) r = t;
  }
  return r;
}

// ---------------------------------------------------------------------------
// Prep Y/Z: one wave per (f, n8-group). lane = col (0..63). Coalesced stores:
// layout [f][n8][col][i], i = atom within group -> per-lane float4/u16x8 runs.
// ---------------------------------------------------------------------------
__global__ __launch_bounds__(256)
void ew_prepYZ(const float* __restrict__ pos, const float* __restrict__ cm,
               float* __restrict__ Yfr, float* __restrict__ Yfi,
               unsigned short* __restrict__ Zpr, unsigned short* __restrict__ Zpi)
{
  const int wv = blockIdx.x * 4 + (threadIdx.x >> 6);
  const int f = wv >> 9;          // / 512
  const int n8 = wv & 511;
  const int col = threadIdx.x & 63;
  const int e = col - 28;
  const int m = (e < 0) ? -e : e;
  const bool valid = col < CD;
  const float by = cm[f * 9 + 4], bz = cm[f * 9 + 8];

  float yr[8], yi[8], zr[8], zi[8];
#pragma unroll
  for (int i = 0; i < 8; ++i) {
    const int n = n8 * 8 + i;
    const bool ok = n < NA;
    const int gn = f * NA + n;
    const float y = ok ? pos[gn * 3 + 1] : 0.f;
    const float z = ok ? pos[gn * 3 + 2] : 0.f;
    {
      float rev = y / by; rev -= floorf(rev);
      float s, c; __sincosf(TWOPI_F * rev, &s, &c);
      float2 r = cpow_m(c, s, m);
      if (e < 0) r.y = -r.y;
      yr[i] = valid ? r.x : 0.f;
      yi[i] = valid ? r.y : 0.f;
    }
    {
      float rev = z / bz; rev -= floorf(rev);
      float s, c; __sincosf(TWOPI_F * rev, &s, &c);
      float2 r = cpow_m(c, s, m);
      if (e < 0) r.y = -r.y;
      zr[i] = valid ? r.x : 0.f;
      zi[i] = valid ? r.y : 0.f;
    }
  }
  const size_t base = (size_t)f * YSTR + (size_t)n8 * 512 + (size_t)col * 8;
  *(float4*)(Yfr + base)     = make_float4(yr[0], yr[1], yr[2], yr[3]);
  *(float4*)(Yfr + base + 4) = make_float4(yr[4], yr[5], yr[6], yr[7]);
  *(float4*)(Yfi + base)     = make_float4(yi[0], yi[1], yi[2], yi[3]);
  *(float4*)(Yfi + base + 4) = make_float4(yi[4], yi[5], yi[6], yi[7]);
  u16x8 zpr, zpi;
#pragma unroll
  for (int i = 0; i < 8; ++i) { zpr[i] = f2bf(zr[i]); zpi[i] = f2bf(zi[i]); }
  *(u16x8*)(Zpr + base) = zpr;
  *(u16x8*)(Zpi + base) = zpi;
}

// ---------------------------------------------------------------------------
// Prep T: thread per (f, n). T[f][a][n] = q * e^{i*a*theta_x}. Coalesced.
// ---------------------------------------------------------------------------
__global__ __launch_bounds__(256)
void ew_prepT(const float* __restrict__ pos, const float* __restrict__ q,
              const float* __restrict__ cm, float2* __restrict__ T)
{
  const int f = blockIdx.y;
  const int n = blockIdx.x * 256 + threadIdx.x;   // 0..4095
  const float bx = cm[f * 9 + 0];
  const bool ok = n < NA;
  const int gn = f * NA + n;
  const float x = ok ? pos[gn * 3 + 0] : 0.f;
  const float qq = ok ? q[gn] : 0.f;
  float rev = x / bx; rev -= floorf(rev);
  float s, c; __sincosf(TWOPI_F * rev, &s, &c);
  const float2 p = make_float2(c, s);
  float2 cur = make_float2(qq, 0.f);
  float2* tp = T + (size_t)f * AD * NPAD + n;
#pragma unroll 1
  for (int a = 0; a < AD; ++a) {
    tp[(size_t)a * NPAD] = cur;
    cur = cmul(cur, p);
  }
}

// ---------------------------------------------------------------------------
// MFMA S-accumulation, K-split. Block = (a, f, chunk), 4 waves.
// Wave w: b-strip [16w,16w+16). Per chunk: 16 k-tiles of 32 atoms.
// Stores raw partial S[ch][f][a][b][c] (float2) to workspace.
// ---------------------------------------------------------------------------
__global__ __launch_bounds__(256)
void ew_smfma(const float* __restrict__ Yfr, const float* __restrict__ Yfi,
              const unsigned short* __restrict__ Zpr,
              const unsigned short* __restrict__ Zpi,
              const float2* __restrict__ T, float2* __restrict__ Sp)
{
  const int a = blockIdx.x, f = blockIdx.y, ch = blockIdx.z;
  const int tid = threadIdx.x;
  const int w = tid >> 6, lane = tid & 63;
  const int g = lane >> 4, r16 = lane & 15;
  const int b0 = 16 * w;

  f32x4 Sr[4], Si[4];
#pragma unroll
  for (int ct = 0; ct < 4; ++ct) {
    Sr[ct] = (f32x4){0.f, 0.f, 0.f, 0.f};
    Si[ct] = (f32x4){0.f, 0.f, 0.f, 0.f};
  }

  const size_t ybase = (size_t)f * YSTR + (size_t)(b0 + r16) * 8 + (size_t)g * 512;
  const size_t zbase = (size_t)f * YSTR + (size_t)r16 * 8 + (size_t)g * 512;
  const float2* tp = T + ((size_t)f * AD + a) * NPAD + g * 8;

  for (int kti = 0; kti < KT_PER_CH; ++kti) {
    const int kt = ch * KT_PER_CH + kti;
    const size_t ko = (size_t)kt * 2048;          // 4 n8-groups * 512 elems
    const float4* t4 = (const float4*)(tp + (size_t)kt * 32);
    const float4 t01 = t4[0], t23 = t4[1], t45 = t4[2], t67 = t4[3];
    const float4* yr4 = (const float4*)(Yfr + ybase + ko);
    const float4* yi4 = (const float4*)(Yfi + ybase + ko);
    const float4 yra = yr4[0], yrb = yr4[1];
    const float4 yia = yi4[0], yib = yi4[1];

    const float tr[8] = {t01.x, t01.z, t23.x, t23.z, t45.x, t45.z, t67.x, t67.z};
    const float ti[8] = {t01.y, t01.w, t23.y, t23.w, t45.y, t45.w, t67.y, t67.w};
    const float yr[8] = {yra.x, yra.y, yra.z, yra.w, yrb.x, yrb.y, yrb.z, yrb.w};
    const float yi[8] = {yia.x, yia.y, yia.z, yia.w, yib.x, yib.y, yib.z, yib.w};

    float ur[8], ui[8];
#pragma unroll
    for (int i = 0; i < 8; ++i) {
      const float mm = ti[i] * yi[i];
      ur[i] = fmaf(tr[i], yr[i], -mm);
      ui[i] = fmaf(tr[i], yi[i], ti[i] * yr[i]);
    }
    union { unsigned u[4]; bfrag v; } UR, UI, UN;
#pragma unroll
    for (int k = 0; k < 4; ++k) {
      asm("v_cvt_pk_bf16_f32 %0, %1, %2" : "=v"(UR.u[k]) : "v"(ur[2*k]), "v"(ur[2*k+1]));
      asm("v_cvt_pk_bf16_f32 %0, %1, %2" : "=v"(UI.u[k]) : "v"(ui[2*k]), "v"(ui[2*k+1]));
    }
#pragma unroll
    for (int k = 0; k < 4; ++k) UN.u[k] = UI.u[k] ^ 0x80008000u;

#pragma unroll
    for (int ct = 0; ct < 4; ++ct) {
      const bfrag Zr8 = *(const bfrag*)(Zpr + zbase + ko + (size_t)ct * 128);
      const bfrag Zi8 = *(const bfrag*)(Zpi + zbase + ko + (size_t)ct * 128);
      Sr[ct] = __builtin_amdgcn_mfma_f32_16x16x32_bf16(UR.v, Zr8, Sr[ct], 0, 0, 0);
      Sr[ct] = __builtin_amdgcn_mfma_f32_16x16x32_bf16(UN.v, Zi8, Sr[ct], 0, 0, 0);
      Si[ct] = __builtin_amdgcn_mfma_f32_16x16x32_bf16(UR.v, Zi8, Si[ct], 0, 0, 0);
      Si[ct] = __builtin_amdgcn_mfma_f32_16x16x32_bf16(UI.v, Zr8, Si[ct], 0, 0, 0);
    }
  }

  // store partial S: D-frag row = b0 + 4g + rg, col = ct*16 + r16
  const size_t sbase = (size_t)ch * SPLANE + ((size_t)f * AD + a) * 4096;
#pragma unroll
  for (int ct = 0; ct < 4; ++ct) {
#pragma unroll
    for (int rg = 0; rg < 4; ++rg) {
      const int b = b0 + 4 * g + rg;
      const int c = ct * 16 + r16;
      Sp[sbase + (size_t)b * 64 + c] = make_float2(Sr[ct][rg], Si[ct][rg]);
    }
  }
}

// ---------------------------------------------------------------------------
// Reduce chunk partials + apply k-space weights (identical formula to R3).
// ---------------------------------------------------------------------------
__global__ __launch_bounds__(256)
void ew_reduce(const float2* __restrict__ Sp, const float* __restrict__ cm,
               float* __restrict__ out)
{
  const int a = blockIdx.y, f = blockIdx.z;
  const int cell = blockIdx.x * 256 + threadIdx.x;   // 0..4095
  const int b = cell >> 6, c = cell & 63;
  float Sr = 0.f, Si = 0.f;
  const size_t base = ((size_t)f * AD + a) * 4096 + cell;
#pragma unroll
  for (int ch = 0; ch < NCH; ++ch) {
    const float2 p = Sp[(size_t)ch * SPLANE + base];
    Sr += p.x; Si += p.y;
  }
  const float bx = cm[f * 9 + 0], by = cm[f * 9 + 4], bz = cm[f * 9 + 8];
  const float invV = 1.f / (bx * by * bz);
  const float fac = (a > 0) ? 2.f : 1.f;
  const float aterm = (float)(a * a) / (bx * bx);
  const int bv = b - 28, cv = c - 28;
  const float ksq = FPI * (aterm + (float)(bv * bv) / (by * by)
                          + (float)(cv * cv) / (bz * bz));
  float val = 0.f;
  if (ksq > 0.f && ksq <= KSQMAX) {
    const float wgt = __expf(-0.5f * ksq) / ksq * fac * invV;
    val = wgt * (Sr * Sr + Si * Si);
  }
  for (int off = 32; off > 0; off >>= 1) val += __shfl_down(val, off);
  __shared__ float wsum[4];
  const int w = threadIdx.x >> 6;
  if ((threadIdx.x & 63) == 0) wsum[w] = val;
  __syncthreads();
  if (threadIdx.x == 0)
    atomicAdd(&out[f], wsum[0] + wsum[1] + wsum[2] + wsum[3]);
}

// ---------------------------------------------------------------------------
// Self-interaction.
// ---------------------------------------------------------------------------
__global__ __launch_bounds__(256)
void ew_self(const float* __restrict__ q, float* __restrict__ out)
{
  const int f = blockIdx.x;
  float s = 0.f;
  for (int i = threadIdx.x; i < NA; i += 256) {
    const float qq = q[f * NA + i];
    s += qq * qq;
  }
  for (int off = 32; off > 0; off >>= 1) s += __shfl_down(s, off);
  __shared__ float wsum[4];
  const int wv = threadIdx.x >> 6;
  if ((threadIdx.x & 63) == 0) wsum[wv] = s;
  __syncthreads();
  if (threadIdx.x == 0)
    atomicAdd(&out[f], -(wsum[0] + wsum[1] + wsum[2] + wsum[3]) * SELF_C);
}

extern "C" void kernel_launch(void* const* d_in, const int* in_sizes, int n_in,
                              void* d_out, int out_size, void* d_ws, size_t ws_size,
                              hipStream_t stream) {
  const float* pos = (const float*)d_in[0];   // (B*N, 3)
  const float* q   = (const float*)d_in[1];   // (B*N, 1)
  const float* cm  = (const float*)d_in[2];   // (B, 3, 3)
  float* out = (float*)d_out;                 // (B,)

  char* ws = (char*)d_ws;
  const size_t MB = 1024 * 1024;
  float* Yfr = (float*)(ws);                       // 4 MB
  float* Yfi = (float*)(ws + 4 * MB);              // 4 MB
  unsigned short* Zpr = (unsigned short*)(ws + 8 * MB);   // 2 MB
  unsigned short* Zpi = (unsigned short*)(ws + 10 * MB);  // 2 MB
  float2* T  = (float2*)(ws + 12 * MB);            // 3.8 MB
  float2* Sp = (float2*)(ws + 16 * MB);            // 30.4 MB (ends 46.4 MB)

  hipMemsetAsync(d_out, 0, out_size * sizeof(float), stream);
  ew_prepYZ<<<dim3(BF * 512 / 4), 256, 0, stream>>>(pos, cm, Yfr, Yfi, Zpr, Zpi);
  ew_prepT<<<dim3(NPAD / 256, BF), 256, 0, stream>>>(pos, q, cm, T);
  ew_smfma<<<dim3(AD, BF, NCH), 256, 0, stream>>>(Yfr, Yfi, Zpr, Zpi, T, Sp);
  ew_reduce<<<dim3(4096 / 256, AD, BF), 256, 0, stream>>>(Sp, cm, out);
  ew_self<<<dim3(BF), 256, 0, stream>>>(q, out);
}